// Round 6
// baseline (98.534 us; speedup 1.0000x reference)
//
#include <hip/hip_runtime.h>
#include <hip/hip_fp16.h>
#include <math.h>

// Problem constants: B=4, M=4096, D=64, W=128
constexpr int B = 4;
constexpr int M = 4096;
constexpr int D = 64;
constexpr int W = 128;
constexpr int NELEM = B * M * D;   // 1,048,576 per tensor

// ---- pass 1: fp32 -> fp16 of k AND v in a single launch ----
__global__ __launch_bounds__(256) void cvt_f32_f16_2(
    const float4* __restrict__ k, const float4* __restrict__ v,
    __half2* __restrict__ kh, __half2* __restrict__ vh, int n4) {
    int i = blockIdx.x * 256 + threadIdx.x;
    const float4* src;
    __half2* dst;
    if (i < n4) { src = k; dst = kh; }
    else        { src = v; dst = vh; i -= n4; if (i >= n4) return; }
    float4 f = src[i];
    dst[2 * i]     = __floats2half2_rn(f.x, f.y);
    dst[2 * i + 1] = __floats2half2_rn(f.z, f.w);
}

// ---- main kernel: one WAVE per (b,m) row; 4 waves (4 m-rows) per block ----
// Grid = B*M/4. Lane (ci,r): ci=lane&7 owns 16B chunk ci; r=lane>>3 covers
// rows w ≡ r (mod 8). Pipeline per wave:
//   issue 16 k gathers -> consume (dot+3-shuffle reduce)
//   -> issue 16 v gathers -> softmax chain (hides v latency) -> consume v.
// voff[] (32-bit byte offsets) computed once, reused for k and v.
__global__ __launch_bounds__(256, 4) void sparse_attn_f16(
    const float* __restrict__ q,
    const __half* __restrict__ kh,
    const __half* __restrict__ vh,
    const int*   __restrict__ idx,
    float*       __restrict__ out)
{
    const int blk  = blockIdx.x;
    const int b    = blk & 3;              // XCD round-robin -> fixed b per XCD
    const int mb   = (blk >> 2) * 4;
    const int t    = threadIdx.x;
    const int wave = t >> 6;
    const int lane = t & 63;
    const int ci   = lane & 7;
    const int r    = lane >> 3;
    const int m    = mb + wave;

    __shared__ int idx_s[4 * W];

    ((int2*)idx_s)[t] = ((const int2*)(idx + (size_t)mb * W))[t];

    const float* qrow = q + ((size_t)b * M + m) * D;
    const float4 qa = ((const float4*)qrow)[2 * ci];
    const float4 qb = ((const float4*)qrow)[2 * ci + 1];

    __syncthreads();   // the only barrier

    // 32-bit byte offsets into the batch's fp16 k/v planes (1 MiB range).
    int voff[16];
    #pragma unroll
    for (int j = 0; j < 16; ++j)
        voff[j] = idx_s[wave * W + j * 8 + r] * (D * 2) + ci * 16;

    const char* kb = (const char*)(kh + (size_t)b * M * D);
    const char* vb = (const char*)(vh + (size_t)b * M * D);

    // ---- k gather: all 16 in flight ----
    float4 kreg[16];
    #pragma unroll
    for (int j = 0; j < 16; ++j)
        kreg[j] = *(const float4*)(kb + voff[j]);

    float larr[16];
    #pragma unroll
    for (int j = 0; j < 16; ++j) {
        const __half2* h = (const __half2*)&kreg[j];
        float2 f0 = __half22float2(h[0]);
        float2 f1 = __half22float2(h[1]);
        float2 f2 = __half22float2(h[2]);
        float2 f3 = __half22float2(h[3]);
        float part = f0.x * qa.x + f0.y * qa.y + f1.x * qa.z + f1.y * qa.w
                   + f2.x * qb.x + f2.y * qb.y + f3.x * qb.z + f3.y * qb.w;
        part += __shfl_xor(part, 1);
        part += __shfl_xor(part, 2);
        part += __shfl_xor(part, 4);
        larr[j] = part;                    // logit for w = j*8 + r
    }

    // ---- v gather issued NOW; softmax chain below hides its latency ----
    float4 vreg[16];
    #pragma unroll
    for (int j = 0; j < 16; ++j)
        vreg[j] = *(const float4*)(vb + voff[j]);

    // ---- softmax, fully in-register ----
    float mx = larr[0];
    #pragma unroll
    for (int j = 1; j < 16; ++j) mx = fmaxf(mx, larr[j]);
    mx = fmaxf(mx, __shfl_xor(mx, 8));
    mx = fmaxf(mx, __shfl_xor(mx, 16));
    mx = fmaxf(mx, __shfl_xor(mx, 32));

    float sum = 0.f;
    #pragma unroll
    for (int j = 0; j < 16; ++j) { larr[j] = __expf(larr[j] - mx); sum += larr[j]; }
    sum += __shfl_xor(sum, 8);
    sum += __shfl_xor(sum, 16);
    sum += __shfl_xor(sum, 32);
    const float inv = 1.0f / sum;   // folded into the final store

    // ---- weighted V accumulate ----
    float acc[8] = {0, 0, 0, 0, 0, 0, 0, 0};
    #pragma unroll
    for (int j = 0; j < 16; ++j) {
        const float p = larr[j];
        const __half2* h = (const __half2*)&vreg[j];
        #pragma unroll
        for (int c = 0; c < 4; ++c) {
            float2 f = __half22float2(h[c]);
            acc[2 * c]     += p * f.x;
            acc[2 * c + 1] += p * f.y;
        }
    }
    #pragma unroll
    for (int o = 8; o < 64; o <<= 1) {
        #pragma unroll
        for (int i = 0; i < 8; ++i) acc[i] += __shfl_xor(acc[i], o);
    }

    if (r == 0) {
        float4* orow = (float4*)(out + ((size_t)b * M + m) * D);
        orow[2 * ci]     = make_float4(acc[0] * inv, acc[1] * inv,
                                       acc[2] * inv, acc[3] * inv);
        orow[2 * ci + 1] = make_float4(acc[4] * inv, acc[5] * inv,
                                       acc[6] * inv, acc[7] * inv);
    }
}

// ---- fallback fp32 kernel (R1 structure) if workspace too small ----
__global__ __launch_bounds__(128) void sparse_attn_f32(
    const float* __restrict__ q,
    const float* __restrict__ k,
    const float* __restrict__ v,
    const int*   __restrict__ idx,
    float*       __restrict__ out)
{
    const int blk = blockIdx.x;
    const int b = blk & 3;
    const int m = blk >> 2;
    const int t = threadIdx.x;
    const int lane = t & 63;
    const int wave = t >> 6;
    const int ci = lane & 15;
    const int r  = lane >> 4;

    __shared__ int   idx_s[W];
    __shared__ float sc_s[W];
    __shared__ float red_s[4];
    __shared__ float4 opart_s[16];

    idx_s[t] = idx[m * W + t];
    const float4 qf = ((const float4*)(q + ((size_t)b * M + m) * D))[ci];
    __syncthreads();

    const float* kb = k + (size_t)b * M * D;
    const int wbase = wave * 64;

    #pragma unroll
    for (int j = 0; j < 16; ++j) {
        const int w = wbase + j * 4 + r;
        const float4 kv = ((const float4*)(kb + (size_t)idx_s[w] * D))[ci];
        float part = kv.x * qf.x + kv.y * qf.y + kv.z * qf.z + kv.w * qf.w;
        part += __shfl_xor(part, 1);
        part += __shfl_xor(part, 2);
        part += __shfl_xor(part, 4);
        part += __shfl_xor(part, 8);
        if (ci == 0) sc_s[w] = part;
    }
    __syncthreads();

    float logit = sc_s[t];
    float mx = logit;
    #pragma unroll
    for (int o = 1; o < 64; o <<= 1) mx = fmaxf(mx, __shfl_xor(mx, o));
    if (lane == 0) red_s[wave] = mx;
    __syncthreads();
    mx = fmaxf(red_s[0], red_s[1]);
    float e = __expf(logit - mx);
    float sm = e;
    #pragma unroll
    for (int o = 1; o < 64; o <<= 1) sm += __shfl_xor(sm, o);
    if (lane == 0) red_s[2 + wave] = sm;
    __syncthreads();
    const float inv_denom = 1.0f / (red_s[2] + red_s[3]);
    sc_s[t] = e * inv_denom;
    __syncthreads();

    const float* vb = v + (size_t)b * M * D;
    float4 acc = {0.f, 0.f, 0.f, 0.f};
    #pragma unroll
    for (int j = 0; j < 16; ++j) {
        const int w = wbase + j * 4 + r;
        const float p = sc_s[w];
        const float4 vv = ((const float4*)(vb + (size_t)idx_s[w] * D))[ci];
        acc.x += p * vv.x; acc.y += p * vv.y;
        acc.z += p * vv.z; acc.w += p * vv.w;
    }
    acc.x += __shfl_xor(acc.x, 16); acc.y += __shfl_xor(acc.y, 16);
    acc.z += __shfl_xor(acc.z, 16); acc.w += __shfl_xor(acc.w, 16);
    acc.x += __shfl_xor(acc.x, 32); acc.y += __shfl_xor(acc.y, 32);
    acc.z += __shfl_xor(acc.z, 32); acc.w += __shfl_xor(acc.w, 32);

    if (wave == 0 && r == 0) opart_s[ci] = acc;
    __syncthreads();
    if (wave == 1 && r == 0) {
        const float4 o0 = opart_s[ci];
        float4 res;
        res.x = o0.x + acc.x; res.y = o0.y + acc.y;
        res.z = o0.z + acc.z; res.w = o0.w + acc.w;
        ((float4*)(out + ((size_t)b * M + m) * D))[ci] = res;
    }
}

extern "C" void kernel_launch(void* const* d_in, const int* in_sizes, int n_in,
                              void* d_out, int out_size, void* d_ws, size_t ws_size,
                              hipStream_t stream) {
    const float* q = (const float*)d_in[0];
    const float* k = (const float*)d_in[1];
    const float* v = (const float*)d_in[2];
    const int* idx = (const int*)d_in[3];
    float* out = (float*)d_out;

    const size_t need = (size_t)2 * NELEM * sizeof(__half);  // 4 MiB
    if (ws_size >= need) {
        __half* kh = (__half*)d_ws;
        __half* vh = kh + NELEM;
        const int n4 = NELEM / 4;
        const int cblk = (2 * n4 + 255) / 256;
        cvt_f32_f16_2<<<cblk, 256, 0, stream>>>((const float4*)k, (const float4*)v,
                                                (__half2*)kh, (__half2*)vh, n4);
        sparse_attn_f16<<<B * M / 4, 256, 0, stream>>>(q, kh, vh, idx, out);
    } else {
        sparse_attn_f32<<<B * M, 128, 0, stream>>>(q, k, v, idx, out);
    }
}

// Round 7
// 93.723 us; speedup vs baseline: 1.0513x; 1.0513x over previous
//
#include <hip/hip_runtime.h>
#include <hip/hip_fp16.h>
#include <math.h>

// Problem constants: B=4, M=4096, D=64, W=128
constexpr int B = 4;
constexpr int M = 4096;
constexpr int D = 64;
constexpr int W = 128;
constexpr int NELEM = B * M * D;   // 1,048,576 per tensor

typedef _Float16 h2_t __attribute__((ext_vector_type(2)));
typedef int      i4_t __attribute__((ext_vector_type(4)));

// ---- pass 1: fp32 -> fp16 of k AND v in a single launch ----
__global__ __launch_bounds__(256) void cvt_f32_f16_2(
    const float4* __restrict__ k, const float4* __restrict__ v,
    __half2* __restrict__ kh, __half2* __restrict__ vh, int n4) {
    int i = blockIdx.x * 256 + threadIdx.x;
    const float4* src;
    __half2* dst;
    if (i < n4) { src = k; dst = kh; }
    else        { src = v; dst = vh; i -= n4; if (i >= n4) return; }
    float4 f = src[i];
    dst[2 * i]     = __floats2half2_rn(f.x, f.y);
    dst[2 * i + 1] = __floats2half2_rn(f.z, f.w);
}

// ---- main kernel: one WAVE per (b,m) row; 4 waves (4 m-rows) per block ----
// Grid = B*M/4. Lane (ci,r): ci=lane&7 owns 16B chunk ci; r=lane>>3 covers
// rows w ≡ r (mod 8). Gathers are NON-TEMPORAL (evict-first in L1): the
// 1 MB/XCD working set gives ~1.5% L1 hit rate, so L1 allocation only
// burns miss-tracking resources; reuse is captured by L2.
// k-dots use v_dot2_f32_f16 (fdot2) with an fp16 q copy.
__global__ __launch_bounds__(256, 4) void sparse_attn_f16(
    const float* __restrict__ q,
    const __half* __restrict__ kh,
    const __half* __restrict__ vh,
    const int*   __restrict__ idx,
    float*       __restrict__ out)
{
    const int blk  = blockIdx.x;
    const int b    = blk & 3;              // XCD round-robin -> fixed b per XCD
    const int mb   = (blk >> 2) * 4;
    const int t    = threadIdx.x;
    const int wave = t >> 6;
    const int lane = t & 63;
    const int ci   = lane & 7;
    const int r    = lane >> 3;
    const int m    = mb + wave;

    __shared__ int idx_s[4 * W];

    ((int2*)idx_s)[t] = ((const int2*)(idx + (size_t)mb * W))[t];

    // q chunk for this lane (dims [ci*8, ci*8+8)) as 4x half2 for fdot2
    const float* qrow = q + ((size_t)b * M + m) * D;
    const float4 qa = ((const float4*)qrow)[2 * ci];
    const float4 qb = ((const float4*)qrow)[2 * ci + 1];
    h2_t qh[4];
    qh[0] = (h2_t){(_Float16)qa.x, (_Float16)qa.y};
    qh[1] = (h2_t){(_Float16)qa.z, (_Float16)qa.w};
    qh[2] = (h2_t){(_Float16)qb.x, (_Float16)qb.y};
    qh[3] = (h2_t){(_Float16)qb.z, (_Float16)qb.w};

    __syncthreads();   // the only barrier

    // 32-bit byte offsets into the batch's fp16 planes; reused for k and v.
    int voff[16];
    #pragma unroll
    for (int j = 0; j < 16; ++j)
        voff[j] = idx_s[wave * W + j * 8 + r] * (D * 2) + ci * 16;

    const char* kb = (const char*)(kh + (size_t)b * M * D);
    const char* vb = (const char*)(vh + (size_t)b * M * D);

    // ---- logits: 2 register batches of 8 nt gathers + fdot2 ----
    float larr[16];
    #pragma unroll
    for (int batch = 0; batch < 2; ++batch) {
        i4_t kreg[8];
        #pragma unroll
        for (int jj = 0; jj < 8; ++jj)
            kreg[jj] = __builtin_nontemporal_load(
                (const i4_t*)(kb + voff[batch * 8 + jj]));
        #pragma unroll
        for (int jj = 0; jj < 8; ++jj) {
            union { i4_t v; h2_t h[4]; } u;
            u.v = kreg[jj];
            float part = 0.f;
            part = __builtin_amdgcn_fdot2(u.h[0], qh[0], part, false);
            part = __builtin_amdgcn_fdot2(u.h[1], qh[1], part, false);
            part = __builtin_amdgcn_fdot2(u.h[2], qh[2], part, false);
            part = __builtin_amdgcn_fdot2(u.h[3], qh[3], part, false);
            part += __shfl_xor(part, 1);
            part += __shfl_xor(part, 2);
            part += __shfl_xor(part, 4);
            larr[batch * 8 + jj] = part;   // logit for w = (batch*8+jj)*8 + r
        }
    }

    // ---- issue first v batch; the softmax chain below hides its latency ----
    i4_t vreg0[8];
    #pragma unroll
    for (int jj = 0; jj < 8; ++jj)
        vreg0[jj] = __builtin_nontemporal_load((const i4_t*)(vb + voff[jj]));

    // ---- softmax, fully in-register ----
    float mx = larr[0];
    #pragma unroll
    for (int j = 1; j < 16; ++j) mx = fmaxf(mx, larr[j]);
    mx = fmaxf(mx, __shfl_xor(mx, 8));
    mx = fmaxf(mx, __shfl_xor(mx, 16));
    mx = fmaxf(mx, __shfl_xor(mx, 32));

    float sum = 0.f;
    #pragma unroll
    for (int j = 0; j < 16; ++j) { larr[j] = __expf(larr[j] - mx); sum += larr[j]; }
    sum += __shfl_xor(sum, 8);
    sum += __shfl_xor(sum, 16);
    sum += __shfl_xor(sum, 32);
    const float inv = 1.0f / sum;   // folded into the final store

    // ---- weighted V accumulate (batch 1 issued while batch 0 consumed) ----
    float acc[8] = {0, 0, 0, 0, 0, 0, 0, 0};
    i4_t vreg1[8];
    #pragma unroll
    for (int jj = 0; jj < 8; ++jj)
        vreg1[jj] = __builtin_nontemporal_load((const i4_t*)(vb + voff[8 + jj]));

    #pragma unroll
    for (int jj = 0; jj < 8; ++jj) {
        const float p = larr[jj];
        union { i4_t v; h2_t h[4]; } u;
        u.v = vreg0[jj];
        #pragma unroll
        for (int c = 0; c < 4; ++c) {
            acc[2 * c]     += p * (float)u.h[c][0];
            acc[2 * c + 1] += p * (float)u.h[c][1];
        }
    }
    #pragma unroll
    for (int jj = 0; jj < 8; ++jj) {
        const float p = larr[8 + jj];
        union { i4_t v; h2_t h[4]; } u;
        u.v = vreg1[jj];
        #pragma unroll
        for (int c = 0; c < 4; ++c) {
            acc[2 * c]     += p * (float)u.h[c][0];
            acc[2 * c + 1] += p * (float)u.h[c][1];
        }
    }
    #pragma unroll
    for (int o = 8; o < 64; o <<= 1) {
        #pragma unroll
        for (int i = 0; i < 8; ++i) acc[i] += __shfl_xor(acc[i], o);
    }

    if (r == 0) {
        float4* orow = (float4*)(out + ((size_t)b * M + m) * D);
        orow[2 * ci]     = make_float4(acc[0] * inv, acc[1] * inv,
                                       acc[2] * inv, acc[3] * inv);
        orow[2 * ci + 1] = make_float4(acc[4] * inv, acc[5] * inv,
                                       acc[6] * inv, acc[7] * inv);
    }
}

// ---- fallback fp32 kernel (R1 structure) if workspace too small ----
__global__ __launch_bounds__(128) void sparse_attn_f32(
    const float* __restrict__ q,
    const float* __restrict__ k,
    const float* __restrict__ v,
    const int*   __restrict__ idx,
    float*       __restrict__ out)
{
    const int blk = blockIdx.x;
    const int b = blk & 3;
    const int m = blk >> 2;
    const int t = threadIdx.x;
    const int lane = t & 63;
    const int wave = t >> 6;
    const int ci = lane & 15;
    const int r  = lane >> 4;

    __shared__ int   idx_s[W];
    __shared__ float sc_s[W];
    __shared__ float red_s[4];
    __shared__ float4 opart_s[16];

    idx_s[t] = idx[m * W + t];
    const float4 qf = ((const float4*)(q + ((size_t)b * M + m) * D))[ci];
    __syncthreads();

    const float* kb = k + (size_t)b * M * D;
    const int wbase = wave * 64;

    #pragma unroll
    for (int j = 0; j < 16; ++j) {
        const int w = wbase + j * 4 + r;
        const float4 kv = ((const float4*)(kb + (size_t)idx_s[w] * D))[ci];
        float part = kv.x * qf.x + kv.y * qf.y + kv.z * qf.z + kv.w * qf.w;
        part += __shfl_xor(part, 1);
        part += __shfl_xor(part, 2);
        part += __shfl_xor(part, 4);
        part += __shfl_xor(part, 8);
        if (ci == 0) sc_s[w] = part;
    }
    __syncthreads();

    float logit = sc_s[t];
    float mx = logit;
    #pragma unroll
    for (int o = 1; o < 64; o <<= 1) mx = fmaxf(mx, __shfl_xor(mx, o));
    if (lane == 0) red_s[wave] = mx;
    __syncthreads();
    mx = fmaxf(red_s[0], red_s[1]);
    float e = __expf(logit - mx);
    float sm = e;
    #pragma unroll
    for (int o = 1; o < 64; o <<= 1) sm += __shfl_xor(sm, o);
    if (lane == 0) red_s[2 + wave] = sm;
    __syncthreads();
    const float inv_denom = 1.0f / (red_s[2] + red_s[3]);
    sc_s[t] = e * inv_denom;
    __syncthreads();

    const float* vb = v + (size_t)b * M * D;
    float4 acc = {0.f, 0.f, 0.f, 0.f};
    #pragma unroll
    for (int j = 0; j < 16; ++j) {
        const int w = wbase + j * 4 + r;
        const float p = sc_s[w];
        const float4 vv = ((const float4*)(vb + (size_t)idx_s[w] * D))[ci];
        acc.x += p * vv.x; acc.y += p * vv.y;
        acc.z += p * vv.z; acc.w += p * vv.w;
    }
    acc.x += __shfl_xor(acc.x, 16); acc.y += __shfl_xor(acc.y, 16);
    acc.z += __shfl_xor(acc.z, 16); acc.w += __shfl_xor(acc.w, 16);
    acc.x += __shfl_xor(acc.x, 32); acc.y += __shfl_xor(acc.y, 32);
    acc.z += __shfl_xor(acc.z, 32); acc.w += __shfl_xor(acc.w, 32);

    if (wave == 0 && r == 0) opart_s[ci] = acc;
    __syncthreads();
    if (wave == 1 && r == 0) {
        const float4 o0 = opart_s[ci];
        float4 res;
        res.x = o0.x + acc.x; res.y = o0.y + acc.y;
        res.z = o0.z + acc.z; res.w = o0.w + acc.w;
        ((float4*)(out + ((size_t)b * M + m) * D))[ci] = res;
    }
}

extern "C" void kernel_launch(void* const* d_in, const int* in_sizes, int n_in,
                              void* d_out, int out_size, void* d_ws, size_t ws_size,
                              hipStream_t stream) {
    const float* q = (const float*)d_in[0];
    const float* k = (const float*)d_in[1];
    const float* v = (const float*)d_in[2];
    const int* idx = (const int*)d_in[3];
    float* out = (float*)d_out;

    const size_t need = (size_t)2 * NELEM * sizeof(__half);  // 4 MiB
    if (ws_size >= need) {
        __half* kh = (__half*)d_ws;
        __half* vh = kh + NELEM;
        const int n4 = NELEM / 4;
        const int cblk = (2 * n4 + 255) / 256;
        cvt_f32_f16_2<<<cblk, 256, 0, stream>>>((const float4*)k, (const float4*)v,
                                                (__half2*)kh, (__half2*)vh, n4);
        sparse_attn_f16<<<B * M / 4, 256, 0, stream>>>(q, kh, vh, idx, out);
    } else {
        sparse_attn_f32<<<B * M, 128, 0, stream>>>(q, k, v, idx, out);
    }
}